// Round 9
// baseline (199.941 us; speedup 1.0000x reference)
//
#include <hip/hip_runtime.h>
#include <hip/hip_bf16.h>
#include <cstdint>
#include <cstddef>

using bf16 = __hip_bfloat16;
typedef __bf16 bf16x8 __attribute__((ext_vector_type(8)));
typedef __bf16 bf16x4 __attribute__((ext_vector_type(4)));
typedef float f32x4 __attribute__((ext_vector_type(4)));

constexpr int BB = 4;
constexpr int TS = 8192;
constexpr int NH = 16;
constexpr int HD = 32;
constexpr int DM = 512;      // NH*HD
constexpr int NQKV = 1536;   // 3*DM
constexpr int NG = 64;       // global tokens

#define MFMA16(a, b, c) __builtin_amdgcn_mfma_f32_16x16x32_bf16((a), (b), (c), 0, 0, 0)

__device__ __forceinline__ bf16x8 ld8(const bf16* p) { return *(const bf16x8*)p; }
__device__ __forceinline__ bf16x4 ld4(const bf16* p) { return *(const bf16x4*)p; }
__device__ __forceinline__ unsigned short b16bits(bf16 v) { return __builtin_bit_cast(unsigned short, v); }

__device__ __forceinline__ void gl_lds16(const bf16* g, void* l) {
  __builtin_amdgcn_global_load_lds((const __attribute__((address_space(1))) void*)g,
                                   (__attribute__((address_space(3))) void*)l, 16, 0, 0);
}

// ---------------------------------------------------------------- prep ------
__global__ void prep_kernel(const float* __restrict__ x,
                            const float* __restrict__ Wq, const float* __restrict__ bq,
                            const float* __restrict__ Wk, const float* __restrict__ bk,
                            const float* __restrict__ Wv, const float* __restrict__ bv,
                            const float* __restrict__ Wo,
                            bf16* __restrict__ xb, bf16* __restrict__ Wt,
                            bf16* __restrict__ Wot, float* __restrict__ bqkv) {
  const int64_t stride = (int64_t)gridDim.x * blockDim.x;
  const int64_t i0 = (int64_t)blockIdx.x * blockDim.x + threadIdx.x;
  const float4* x4 = (const float4*)x;
  ushort4* xb4 = (ushort4*)xb;
  for (int64_t i = i0; i < (int64_t)BB * TS * DM / 4; i += stride) {
    float4 v = x4[i];
    ushort4 o;
    o.x = b16bits(__float2bfloat16(v.x));
    o.y = b16bits(__float2bfloat16(v.y));
    o.z = b16bits(__float2bfloat16(v.z));
    o.w = b16bits(__float2bfloat16(v.w));
    xb4[i] = o;
  }
  for (int64_t i = i0; i < (int64_t)NQKV * DM; i += stride) {
    const int n = (int)(i >> 9), k = (int)(i & 511);
    const float* W = (n < 512) ? Wq : ((n < 1024) ? Wk : Wv);
    Wt[i] = __float2bfloat16(W[(size_t)k * DM + (n & 511)]);
  }
  for (int64_t i = i0; i < (int64_t)DM * DM; i += stride) {
    const int n = (int)(i >> 9), k = (int)(i & 511);
    Wot[i] = __float2bfloat16(Wo[(size_t)k * DM + n]);
  }
  for (int64_t i = i0; i < NQKV; i += stride)
    bqkv[i] = (i < 512) ? bq[i] : ((i < 1024) ? bk[i - 512] : bv[i - 1024]);
}

// ---------------------------------------------------------------- GEMM ------
// C[M,N] = A[M,K] @ Bt[N,K]^T + bias[N].  128x128 tile, BK=64, 4 waves,
// 64 KB LDS double-buffer, counted vmcnt(8) (round-6 proven body), PLUS a
// persistent m-tile loop (MTILES consecutive m-tiles per block): stage of
// tile mi+1's kt=0 is issued during tile mi's last K-step (its buffer was
// freed at kt=KT-2's end barrier), and tile mi's C-epilogue runs UNDER those
// in-flight loads (loads return in-order among loads, so the next vmcnt(8)
// still guarantees the prefetch landed; epilogue stores only lengthen it).
// V-blocks (WVT && n0>=1024) restart the pipeline per tile: their transpose
// epilogue uses smem as scratch, so they drain with vmcnt(0) first.
// XCD-aware bid swizzle (grid divisible by 8; cpx = grid/8).
template <bool F32OUT, bool WVT, int MTILES>
__global__ __launch_bounds__(256) void gemm_bias(const bf16* __restrict__ A,
                                                 const bf16* __restrict__ Bt,
                                                 const float* __restrict__ bias,
                                                 void* __restrict__ Cv,
                                                 bf16* __restrict__ vt,
                                                 int M, int N, int K, int cpx) {
  __shared__ __attribute__((aligned(16))) char smem[65536];
  const int tid = threadIdx.x;
  const int lane = tid & 63, wid = tid >> 6;
  const int grp = lane >> 4, col = lane & 15;
  const int bid = (blockIdx.x & 7) * cpx + (blockIdx.x >> 3);
  const int NT = N >> 7;
  const int mg = bid / NT, nt = bid % NT;
  const int m0b = mg * (MTILES << 7), n0 = nt << 7;
  const int wm = wid >> 1, wn = wid & 1;
  const int KT = K >> 6;
  const bool vblk = WVT && (n0 >= 1024);
  f32x4 acc[4][4] = {};

  auto stage = [&](int mi, int kt) {
    char* buf = smem + (kt & 1) * 16384;
    const int m0 = m0b + (mi << 7);
    #pragma unroll
    for (int c = 0; c < 4; ++c) {
      const int chunk = wid * 4 + c;              // 0..15, wave-uniform
      const int row = chunk * 8 + (lane >> 3);    // 0..127
      const int sl = lane & 7;                    // linear 16B slot in row
      const int koff = ((sl ^ (row & 7)) << 3) + (kt << 6);  // inverse-swizzled k
      gl_lds16(A + (size_t)(m0 + row) * K + koff, buf + chunk * 1024);
      gl_lds16(Bt + (size_t)(n0 + row) * K + koff, buf + 32768 + chunk * 1024);
    }
  };

  for (int mi = 0; mi < MTILES; ++mi) {
    if (vblk || mi == 0) stage(mi, 0);   // non-V mi>0: issued during prev tile
    for (int kt = 0; kt < KT; ++kt) {
      if (kt + 1 < KT)                        stage(mi, kt + 1);
      else if (!vblk && mi + 1 < MTILES)      stage(mi + 1, 0);
      const bool more = (kt + 1 < KT) || (!vblk && mi + 1 < MTILES);
      __builtin_amdgcn_sched_barrier(0);
      if (more) asm volatile("s_waitcnt vmcnt(8)" ::: "memory");
      else      asm volatile("s_waitcnt vmcnt(0)" ::: "memory");
      __builtin_amdgcn_sched_barrier(0);
      __builtin_amdgcn_s_barrier();            // this K-step's loads landed
      __builtin_amdgcn_sched_barrier(0);
      const char* sA = smem + (kt & 1) * 16384;
      const char* sB = sA + 32768;
      #pragma unroll
      for (int ks = 0; ks < 2; ++ks) {
        bf16x8 af[4], bfr[4];
        #pragma unroll
        for (int f = 0; f < 4; ++f) {
          const int ra = wm * 64 + f * 16 + col;
          af[f] = *(const bf16x8*)(sA + ra * 128 + (((ks * 4 + grp) ^ (ra & 7)) << 4));
          const int rb = wn * 64 + f * 16 + col;
          bfr[f] = *(const bf16x8*)(sB + rb * 128 + (((ks * 4 + grp) ^ (rb & 7)) << 4));
        }
        #pragma unroll
        for (int i = 0; i < 4; ++i)
          #pragma unroll
          for (int j = 0; j < 4; ++j)
            acc[i][j] = MFMA16(af[i], bfr[j], acc[i][j]);
      }
      __builtin_amdgcn_sched_barrier(0);
      __builtin_amdgcn_s_barrier();   // buf[kt&1] reads done; free to overwrite
      __builtin_amdgcn_sched_barrier(0);
    }
    // ---- epilogue for tile mi (overlaps next tile's in-flight prefetch) ----
    const int m0 = m0b + (mi << 7);
    if (!vblk) {
      #pragma unroll
      for (int i = 0; i < 4; ++i)
        #pragma unroll
        for (int j = 0; j < 4; ++j) {
          const int n = n0 + wn * 64 + j * 16 + col;
          const float bz = bias[n];
          #pragma unroll
          for (int r = 0; r < 4; ++r) {
            const int m = m0 + wm * 64 + i * 16 + grp * 4 + r;
            const float v = acc[i][j][r] + bz;
            if (F32OUT)
              ((float*)Cv)[(size_t)m * N + n] = v;
            else
              ((bf16*)Cv)[(size_t)m * N + n] = __float2bfloat16(v);
          }
        }
    } else {
      // all loads drained (vmcnt(0) at kt=KT-1) and all waves past the end
      // barrier: smem is free for the transpose scratch.
      bf16* lt = (bf16*)smem;   // [128][136], XOR-16 swizzle
      #pragma unroll
      for (int i = 0; i < 4; ++i)
        #pragma unroll
        for (int j = 0; j < 4; ++j) {
          const int nl = wn * 64 + j * 16 + col;
          const float bz = bias[n0 + nl];
          #pragma unroll
          for (int r = 0; r < 4; ++r) {
            const int ml = wm * 64 + i * 16 + grp * 4 + r;
            lt[nl * 136 + (ml ^ ((nl & 7) << 4))] = __float2bfloat16(acc[i][j][r] + bz);
          }
        }
      __syncthreads();
      const int row = tid >> 1, half = tid & 1;
      const int b = m0 >> 13, t0 = m0 & 8191;
      bf16* dst = vt + (size_t)(b * DM + (n0 & 511) + row) * TS + t0 + half * 64;
      const bf16* srcl = lt + row * 136;
      #pragma unroll
      for (int c = 0; c < 8; ++c)
        *(bf16x8*)(dst + c * 8) =
            *(const bf16x8*)(srcl + ((half * 64 + c * 8) ^ ((row & 7) << 4)));
      __syncthreads();  // lt reads done before next tile's stage clobbers smem
    }
    if (mi + 1 < MTILES) {
      #pragma unroll
      for (int i = 0; i < 4; ++i)
        #pragma unroll
        for (int j = 0; j < 4; ++j)
          acc[i][j] = f32x4{0.f, 0.f, 0.f, 0.f};
    }
  }
}

// --------------------------------------------------------------- vgt --------
// vgt[(b*NH+h)*HD+dv][g] = vt[row][gidx[g]]; zeroes vt front/tail pads.
__global__ void vgt_kernel(const bf16* __restrict__ vt, const int* __restrict__ gidx,
                           bf16* __restrict__ vtp, bf16* __restrict__ vgt) {
  const int64_t stride = (int64_t)gridDim.x * blockDim.x;
  const int64_t i0 = (int64_t)blockIdx.x * blockDim.x + threadIdx.x;
  for (int64_t i = i0; i < 512; i += stride) {
    if (i < 64) vtp[i - 64] = __float2bfloat16(0.f);
    else vtp[(size_t)2048 * TS + (i - 64)] = __float2bfloat16(0.f);
  }
  for (int64_t i = i0; i < (int64_t)2048 * NG; i += stride) {
    const int row = (int)(i >> 6), g = (int)(i & 63);
    const int gi = gidx[g];
    vgt[i] = vt[(size_t)row * TS + gi];
  }
}

// --------------------------------------------------------------- attn -------
// Block = 64 queries of one (b,h); 4 waves x 16 queries. Swapped QK^T
// (s = mfma(K,Q)) puts each query's full score row on 4 lanes {col, col+16,
// col+32, col+48}: softmax = 2 shuffles, P stays IN REGISTERS (no LDS
// roundtrip). PV: 16x16x32 MFMA where abstract k = grp*8+{0..7} covers keys
// {f0*16+grp*4+0..3, f1*16+grp*4+0..3} in BOTH operands -> two 16-key blocks
// per MFMA, B-frag = lane's own packed P, A-frag = 2x ds_read_b64 from V^T.
__global__ __launch_bounds__(256) void attn_kernel(const bf16* __restrict__ qkv,
                                                   const bf16* __restrict__ vt,
                                                   const bf16* __restrict__ vgt,
                                                   const int* __restrict__ gidx,
                                                   bf16* __restrict__ ctx) {
  constexpr int VST = 216;
  constexpr int VGST = 88;
  __shared__ __attribute__((aligned(16))) char smem[35840];
  bf16* sV = (bf16*)smem;             // 13824 B
  bf16* sVg = (bf16*)(smem + 13824);  //  5632 B
  bf16* sK = (bf16*)(smem + 19456);   // 12288 B
  bf16* sKg = (bf16*)(smem + 31744);  //  4096 B

  const int tid = threadIdx.x, wid = tid >> 6, lane = tid & 63;
  const int grp = lane >> 4, col = lane & 15;
  const int bid = (blockIdx.x & 7) * 1024 + (blockIdx.x >> 3);
  const int tile = bid & 127, h = (bid >> 7) & 15, b = bid >> 11;
  const int t0b = tile * 64;
  const int kbb = t0b - 64;
  const int bh = b * NH + h;
  const bf16* base = qkv + (size_t)b * TS * NQKV;
  const bf16* kpl = base + 512 + h * 32;

  // ---- cooperative staging ----
  #pragma unroll
  for (int it = 0; it < 3; ++it) {             // sK: 768 16B chunks, direct-to-LDS
    const int idx = it * 256 + tid;
    const int row = idx >> 2, part = idx & 3;
    const int tok = min(max(kbb + row, 0), TS - 1);
    gl_lds16(kpl + (size_t)tok * NQKV + ((part ^ (row & 3)) << 3), sK + idx * 8);
  }
  {
    const int row = tid >> 2, part = tid & 3;  // sKg: 256 chunks, direct-to-LDS
    const int gi = gidx[row];
    gl_lds16(kpl + (size_t)gi * NQKV + ((part ^ (row & 3)) << 3), sKg + tid * 8);
  }
  {
    const bf16* vr = vt + (size_t)(bh * HD + (tid >> 3)) * TS + kbb;
    #pragma unroll
    for (int i = 0; i < 4; ++i) {              // sV: 32 rows x 27 chunks
      const int c = i * 8 + (tid & 7);
      if (c < 27) *(bf16x8*)(sV + (tid >> 3) * VST + c * 8) = ld8(vr + c * 8);
    }
  }
  {
    const int row = tid >> 3, c = tid & 7;     // sVg: 256 chunks
    *(bf16x8*)(sVg + row * VGST + c * 8) = ld8(vgt + (size_t)(bh * HD + row) * NG + c * 8);
  }
  __syncthreads();

  // ---- per-wave compute ----
  const int qt = t0b + wid * 16;
  const int offw = wid * 16;

  const bf16x8 qf = ld8(base + (size_t)(qt + col) * NQKV + h * 32 + grp * 8);
  const f32x4 z = {0.f, 0.f, 0.f, 0.f};
  f32x4 s[13];
  #pragma unroll
  for (int f = 0; f < 9; ++f) {
    const int row = offw + f * 16 + col;
    bf16x8 kf = ld8(sK + row * 32 + ((grp ^ (row & 3)) << 3));
    s[f] = MFMA16(kf, qf, z);   // swapped: D[key_local][q]
  }
  #pragma unroll
  for (int f = 0; f < 4; ++f) {
    const int row = f * 16 + col;
    bf16x8 kf = ld8(sKg + row * 32 + ((grp ^ (row & 3)) << 3));
    s[9 + f] = MFMA16(kf, qf, z);
  }
  // lane (grp,col): query q=col, local key j = f*16 + grp*4 + r
  const float scale = 0.17677669529663688f;  // 1/sqrt(32)
  float mx = -3e38f;
  const bool interior = (tile >= 1) & (tile <= 126);
  if (interior) {
    #pragma unroll
    for (int f = 0; f < 13; ++f) {
      #pragma unroll
      for (int r = 0; r < 4; ++r) {
        float v = s[f][r] * scale;
        if (f == 0) v = (grp * 4 + r >= col) ? v : -1e30f;
        if (f == 8) v = (grp * 4 + r <= col) ? v : -1e30f;
        s[f][r] = v;
        mx = fmaxf(mx, v);
      }
    }
  } else {
    #pragma unroll
    for (int f = 0; f < 13; ++f) {
      #pragma unroll
      for (int r = 0; r < 4; ++r) {
        float v = s[f][r] * scale;
        if (f < 9) {
          const int j = f * 16 + grp * 4 + r;
          const int pos = qt - 64 + j;
          const bool valid = (j >= col) & (j <= col + 128) & (pos >= 0) & (pos < TS);
          v = valid ? v : -1e30f;
        }
        s[f][r] = v;
        mx = fmaxf(mx, v);
      }
    }
  }
  mx = fmaxf(mx, __shfl_xor(mx, 16));
  mx = fmaxf(mx, __shfl_xor(mx, 32));
  float sum = 0.f;
  bf16x8 pb[7];  // pairs (0,1),(2,3),(4,5),(6,7),(8,zero),(9,10),(11,12)
  #pragma unroll
  for (int f = 0; f < 13; ++f) {
    const int pr = (f < 9) ? (f >> 1) : (5 + ((f - 9) >> 1));
    const int hf = (f < 9) ? (f & 1) : ((f - 9) & 1);
    #pragma unroll
    for (int r = 0; r < 4; ++r) {
      float p = __expf(s[f][r] - mx);
      sum += p;
      pb[pr][hf * 4 + r] = (__bf16)__float2bfloat16(p);
    }
  }
  #pragma unroll
  for (int r = 0; r < 4; ++r) pb[4][4 + r] = (__bf16)__float2bfloat16(0.f);
  sum += __shfl_xor(sum, 16);
  sum += __shfl_xor(sum, 32);
  const float sm = 1.0f / sum;

  f32x4 c0 = z, c1 = z;
  const bf16* sVr0 = sV + col * VST;
  const bf16* sVr1 = sV + (col + 16) * VST;
  #pragma unroll
  for (int i = 0; i < 5; ++i) {     // local key pairs (32 keys per MFMA)
    const int kk = offw + i * 32 + grp * 4;
    bf16x8 a0 = __builtin_shufflevector(ld4(sVr0 + kk), ld4(sVr0 + kk + 16),
                                        0, 1, 2, 3, 4, 5, 6, 7);
    bf16x8 a1 = __builtin_shufflevector(ld4(sVr1 + kk), ld4(sVr1 + kk + 16),
                                        0, 1, 2, 3, 4, 5, 6, 7);
    c0 = MFMA16(a0, pb[i], c0);
    c1 = MFMA16(a1, pb[i], c1);
  }
  const bf16* sVg0 = sVg + col * VGST;
  const bf16* sVg1 = sVg + (col + 16) * VGST;
  #pragma unroll
  for (int i = 0; i < 2; ++i) {     // global key pairs
    const int kk = i * 32 + grp * 4;
    bf16x8 a0 = __builtin_shufflevector(ld4(sVg0 + kk), ld4(sVg0 + kk + 16),
                                        0, 1, 2, 3, 4, 5, 6, 7);
    bf16x8 a1 = __builtin_shufflevector(ld4(sVg1 + kk), ld4(sVg1 + kk + 16),
                                        0, 1, 2, 3, 4, 5, 6, 7);
    c0 = MFMA16(a0, pb[5 + i], c0);
    c1 = MFMA16(a1, pb[5 + i], c1);
  }
  // lane (grp,col) holds ctx^T[dv = grp*4+r (+16)][q = col]
  const int t = qt + col;
  bf16* op = ctx + ((size_t)(b * TS + t)) * DM + h * 32 + grp * 4;
  ushort4 o0, o1;
  o0.x = b16bits(__float2bfloat16(c0[0] * sm));
  o0.y = b16bits(__float2bfloat16(c0[1] * sm));
  o0.z = b16bits(__float2bfloat16(c0[2] * sm));
  o0.w = b16bits(__float2bfloat16(c0[3] * sm));
  o1.x = b16bits(__float2bfloat16(c1[0] * sm));
  o1.y = b16bits(__float2bfloat16(c1[1] * sm));
  o1.z = b16bits(__float2bfloat16(c1[2] * sm));
  o1.w = b16bits(__float2bfloat16(c1[3] * sm));
  *(ushort4*)op = o0;
  *(ushort4*)(op + 16) = o1;
}

// ------------------------------------------------------------- launch -------
extern "C" void kernel_launch(void* const* d_in, const int* in_sizes, int n_in,
                              void* d_out, int out_size, void* d_ws, size_t ws_size,
                              hipStream_t stream) {
  (void)in_sizes; (void)n_in; (void)out_size; (void)ws_size;
  const float* x = (const float*)d_in[0];
  const float* Wq = (const float*)d_in[1];
  const float* bq = (const float*)d_in[2];
  const float* Wk = (const float*)d_in[3];
  const float* bk = (const float*)d_in[4];
  const float* Wv = (const float*)d_in[5];
  const float* bv = (const float*)d_in[6];
  const float* Wo = (const float*)d_in[7];
  const float* bo = (const float*)d_in[8];
  const int* gidx = (const int*)d_in[9];
  float* out = (float*)d_out;

  char* ws = (char*)d_ws;
  size_t off = 0;
  auto alloc = [&](size_t bytes) -> void* {
    void* p = ws + off;
    off += (bytes + 255) & ~(size_t)255;
    return p;
  };
  bf16* xb = (bf16*)alloc((size_t)BB * TS * DM * 2);       // 32 MB (reused as ctx)
  bf16* Wt = (bf16*)alloc((size_t)NQKV * DM * 2);          // 1.5 MB
  bf16* Wot = (bf16*)alloc((size_t)DM * DM * 2);           // 0.5 MB
  float* bqkv = (float*)alloc((size_t)NQKV * 4);           // 6 KB
  bf16* qkv = (bf16*)alloc((size_t)BB * TS * NQKV * 2);    // 96 MB (V third unused)
  bf16* vta = (bf16*)alloc(((size_t)2048 * TS + 512) * 2); // 32 MB + pad
  bf16* vgt = (bf16*)alloc((size_t)2048 * NG * 2);         // 256 KB
  bf16* ctx = xb;                                          // alias: xb dead after GEMM1
  bf16* vt = vta + 64;                                     // front pad of 64 elems

  prep_kernel<<<dim3(2048), dim3(256), 0, stream>>>(x, Wq, bq, Wk, bk, Wv, bv, Wo,
                                                    xb, Wt, Wot, bqkv);
  gemm_bias<false, true, 2><<<dim3(1536), dim3(256), 0, stream>>>(
      xb, Wt, bqkv, qkv, vt, BB * TS, NQKV, DM, 192);
  vgt_kernel<<<dim3(512), dim3(256), 0, stream>>>(vt, gidx, vt, vgt);
  attn_kernel<<<dim3(8192), dim3(256), 0, stream>>>(qkv, vt, vgt, gidx, ctx);
  gemm_bias<true, false, 2><<<dim3(512), dim3(256), 0, stream>>>(
      ctx, Wot, bo, out, nullptr, BB * TS, DM, DM, 64);
}

// Round 10
// 168.036 us; speedup vs baseline: 1.1899x; 1.1899x over previous
//
#include <hip/hip_runtime.h>
#include <hip/hip_bf16.h>
#include <cstdint>
#include <cstddef>

using bf16 = __hip_bfloat16;
typedef __bf16 bf16x8 __attribute__((ext_vector_type(8)));
typedef __bf16 bf16x4 __attribute__((ext_vector_type(4)));
typedef float f32x4 __attribute__((ext_vector_type(4)));

constexpr int BB = 4;
constexpr int TS = 8192;
constexpr int NH = 16;
constexpr int HD = 32;
constexpr int DM = 512;      // NH*HD
constexpr int NQKV = 1536;   // 3*DM
constexpr int NG = 64;       // global tokens

#define MFMA16(a, b, c) __builtin_amdgcn_mfma_f32_16x16x32_bf16((a), (b), (c), 0, 0, 0)

__device__ __forceinline__ bf16x8 ld8(const bf16* p) { return *(const bf16x8*)p; }
__device__ __forceinline__ bf16x4 ld4(const bf16* p) { return *(const bf16x4*)p; }
__device__ __forceinline__ unsigned short b16bits(bf16 v) { return __builtin_bit_cast(unsigned short, v); }

__device__ __forceinline__ void gl_lds16(const bf16* g, void* l) {
  __builtin_amdgcn_global_load_lds((const __attribute__((address_space(1))) void*)g,
                                   (__attribute__((address_space(3))) void*)l, 16, 0, 0);
}

// ---------------------------------------------------------------- prep ------
// Builds xb (bf16 cast of x), bqkv (fused bias), and FRAGMENT-PACKED weights:
// Wp  [nt<12][wn<2][kt<8][ks<2][f<4][lane<64][8]  (QKV weights, transposed)
// Wp2 [nt< 4][wn<2][kt<8][ks<2][f<4][lane<64][8]  (Wo, transposed)
// Element (chunk c, lane l, j): n = nt*128+wn*64+f*16+(l&15),
// k = kt*64+ks*32+(l>>4)*8+j, value = W[k][n] — so a wave's B-fragment is one
// contiguous, fully-coalesced 1KB load.
__global__ void prep_kernel(const float* __restrict__ x,
                            const float* __restrict__ Wq, const float* __restrict__ bq,
                            const float* __restrict__ Wk, const float* __restrict__ bk,
                            const float* __restrict__ Wv, const float* __restrict__ bv,
                            const float* __restrict__ Wo,
                            bf16* __restrict__ xb, bf16* __restrict__ Wp,
                            bf16* __restrict__ Wp2, float* __restrict__ bqkv) {
  const int64_t stride = (int64_t)gridDim.x * blockDim.x;
  const int64_t i0 = (int64_t)blockIdx.x * blockDim.x + threadIdx.x;
  const float4* x4 = (const float4*)x;
  ushort4* xb4 = (ushort4*)xb;
  for (int64_t i = i0; i < (int64_t)BB * TS * DM / 4; i += stride) {
    float4 v = x4[i];
    ushort4 o;
    o.x = b16bits(__float2bfloat16(v.x));
    o.y = b16bits(__float2bfloat16(v.y));
    o.z = b16bits(__float2bfloat16(v.z));
    o.w = b16bits(__float2bfloat16(v.w));
    xb4[i] = o;
  }
  // Wp: 98304 chunks of 8
  for (int64_t c = i0; c < (int64_t)NQKV * DM / 8; c += stride) {
    const int lane = (int)(c & 63), f = (int)((c >> 6) & 3), ks = (int)((c >> 8) & 1);
    const int kt = (int)((c >> 9) & 7), wn = (int)((c >> 12) & 1), nt = (int)(c >> 13);
    const int n = nt * 128 + wn * 64 + f * 16 + (lane & 15);
    const int k = kt * 64 + ks * 32 + (lane >> 4) * 8;
    const float* W = (n < 512) ? Wq : ((n < 1024) ? Wk : Wv);
    const int nn = n & 511;
    #pragma unroll
    for (int j = 0; j < 8; ++j)
      Wp[c * 8 + j] = __float2bfloat16(W[(size_t)(k + j) * DM + nn]);
  }
  // Wp2: 32768 chunks of 8
  for (int64_t c = i0; c < (int64_t)DM * DM / 8; c += stride) {
    const int lane = (int)(c & 63), f = (int)((c >> 6) & 3), ks = (int)((c >> 8) & 1);
    const int kt = (int)((c >> 9) & 7), wn = (int)((c >> 12) & 1), nt = (int)(c >> 13);
    const int n = nt * 128 + wn * 64 + f * 16 + (lane & 15);
    const int k = kt * 64 + ks * 32 + (lane >> 4) * 8;
    #pragma unroll
    for (int j = 0; j < 8; ++j)
      Wp2[c * 8 + j] = __float2bfloat16(Wo[(size_t)(k + j) * DM + n]);
  }
  for (int64_t i = i0; i < NQKV; i += stride)
    bqkv[i] = (i < 512) ? bq[i] : ((i < 1024) ? bk[i - 512] : bv[i - 1024]);
}

// ---------------------------------------------------------------- GEMM ------
// C[M,N] = A[M,K] @ B^T + bias[N].  128x128 tile, BK=64, 4 waves.
// A: gl_lds -> 32KB LDS double-buffer (XOR-swizzled), counted vmcnt.
// B: fragment-packed Wp, loaded STRAIGHT TO REGISTERS (1KB coalesced loads,
// L2-hot) — halves LDS read traffic (the measured ~680TF ceiling was LDS-BW).
// vmcnt queue at the wait: {A(kt) 4, B(kt) 8, A(kt+1) 4} -> vmcnt(4) drains
// exactly A(kt)+B(kt). B(kt+1) issued after its regs' last read (WAR-safe).
// WVT: for n0>=1024 (V third) the tile is transposed through LDS and written
// to vt[b*512 + (n&511)][t] in coalesced 16B chunks.
template <bool F32OUT, bool WVT>
__global__ __launch_bounds__(256, 3) void gemm_bias(const bf16* __restrict__ A,
                                                    const bf16* __restrict__ Bp,
                                                    const float* __restrict__ bias,
                                                    void* __restrict__ Cv,
                                                    bf16* __restrict__ vt,
                                                    int M, int N, int K, int cpx) {
  __shared__ __attribute__((aligned(16))) char smem[35072];
  const int tid = threadIdx.x;
  const int lane = tid & 63, wid = tid >> 6;
  const int grp = lane >> 4, col = lane & 15;
  const int bid = (blockIdx.x & 7) * cpx + (blockIdx.x >> 3);
  const int NT = N >> 7;
  const int mt = bid / NT, nt = bid % NT;
  const int m0 = mt << 7, n0 = nt << 7;
  const int wm = wid >> 1, wn = wid & 1;
  const int KT = K >> 6;
  f32x4 acc[4][4] = {};

  const bf16* bp = Bp + (size_t)(nt * 2 + wn) * KT * 4096 + lane * 8;
  bf16x8 breg[2][4];
  auto loadB = [&](int kt) {
    #pragma unroll
    for (int ks = 0; ks < 2; ++ks)
      #pragma unroll
      for (int f = 0; f < 4; ++f)
        breg[ks][f] = ld8(bp + (size_t)(kt * 8 + ks * 4 + f) * 512);
  };
  auto stageA = [&](int kt) {
    char* buf = smem + (kt & 1) * 16384;
    #pragma unroll
    for (int c = 0; c < 4; ++c) {
      const int chunk = wid * 4 + c;              // 0..15, wave-uniform
      const int row = chunk * 8 + (lane >> 3);    // 0..127
      const int sl = lane & 7;                    // linear 16B slot in row
      const int koff = ((sl ^ (row & 7)) << 3) + (kt << 6);  // inverse-swizzled k
      gl_lds16(A + (size_t)(m0 + row) * K + koff, buf + chunk * 1024);
    }
  };

  stageA(0);
  loadB(0);
  for (int kt = 0; kt < KT; ++kt) {
    if (kt + 1 < KT) {
      stageA(kt + 1);
      __builtin_amdgcn_sched_barrier(0);
      asm volatile("s_waitcnt vmcnt(4)" ::: "memory");  // A(kt)+B(kt) landed
    } else {
      __builtin_amdgcn_sched_barrier(0);
      asm volatile("s_waitcnt vmcnt(0)" ::: "memory");
    }
    __builtin_amdgcn_sched_barrier(0);
    __builtin_amdgcn_s_barrier();            // all waves' A(kt) in LDS
    __builtin_amdgcn_sched_barrier(0);
    const char* sA = smem + (kt & 1) * 16384;
    #pragma unroll
    for (int ks = 0; ks < 2; ++ks) {
      bf16x8 af[4];
      #pragma unroll
      for (int f = 0; f < 4; ++f) {
        const int ra = wm * 64 + f * 16 + col;
        af[f] = *(const bf16x8*)(sA + ra * 128 + (((ks * 4 + grp) ^ (ra & 7)) << 4));
      }
      #pragma unroll
      for (int i = 0; i < 4; ++i)
        #pragma unroll
        for (int j = 0; j < 4; ++j)
          acc[i][j] = MFMA16(af[i], breg[ks][j], acc[i][j]);
    }
    if (kt + 1 < KT) loadB(kt + 1);  // after breg's last read this iteration
    __builtin_amdgcn_sched_barrier(0);
    __builtin_amdgcn_s_barrier();    // A buf[kt&1] reads done; free to overwrite
    __builtin_amdgcn_sched_barrier(0);
  }

  const bool wv = WVT && (n0 >= 1024);
  if (!wv) {
    #pragma unroll
    for (int i = 0; i < 4; ++i)
      #pragma unroll
      for (int j = 0; j < 4; ++j) {
        const int n = n0 + wn * 64 + j * 16 + col;
        const float bz = bias[n];
        #pragma unroll
        for (int r = 0; r < 4; ++r) {
          const int m = m0 + wm * 64 + i * 16 + grp * 4 + r;
          const float v = acc[i][j][r] + bz;
          if (F32OUT)
            ((float*)Cv)[(size_t)m * N + n] = v;
          else
            ((bf16*)Cv)[(size_t)m * N + n] = __float2bfloat16(v);
        }
      }
  } else {
    __syncthreads();  // K-loop done for all waves; smem free as scratch
    bf16* lt = (bf16*)smem;   // [128][136], XOR-16 swizzle (34816 B <= 35072)
    #pragma unroll
    for (int i = 0; i < 4; ++i)
      #pragma unroll
      for (int j = 0; j < 4; ++j) {
        const int nl = wn * 64 + j * 16 + col;
        const float bz = bias[n0 + nl];
        #pragma unroll
        for (int r = 0; r < 4; ++r) {
          const int ml = wm * 64 + i * 16 + grp * 4 + r;
          lt[nl * 136 + (ml ^ ((nl & 7) << 4))] = __float2bfloat16(acc[i][j][r] + bz);
        }
      }
    __syncthreads();
    const int row = tid >> 1, half = tid & 1;
    const int b = m0 >> 13, t0 = m0 & 8191;
    bf16* dst = vt + (size_t)(b * DM + (n0 & 511) + row) * TS + t0 + half * 64;
    const bf16* srcl = lt + row * 136;
    #pragma unroll
    for (int c = 0; c < 8; ++c)
      *(bf16x8*)(dst + c * 8) =
          *(const bf16x8*)(srcl + ((half * 64 + c * 8) ^ ((row & 7) << 4)));
  }
}

// --------------------------------------------------------------- vgt --------
// vgt[(b*NH+h)*HD+dv][g] = vt[row][gidx[g]]; zeroes vt front/tail pads.
__global__ void vgt_kernel(const bf16* __restrict__ vt, const int* __restrict__ gidx,
                           bf16* __restrict__ vtp, bf16* __restrict__ vgt) {
  const int64_t stride = (int64_t)gridDim.x * blockDim.x;
  const int64_t i0 = (int64_t)blockIdx.x * blockDim.x + threadIdx.x;
  for (int64_t i = i0; i < 512; i += stride) {
    if (i < 64) vtp[i - 64] = __float2bfloat16(0.f);
    else vtp[(size_t)2048 * TS + (i - 64)] = __float2bfloat16(0.f);
  }
  for (int64_t i = i0; i < (int64_t)2048 * NG; i += stride) {
    const int row = (int)(i >> 6), g = (int)(i & 63);
    const int gi = gidx[g];
    vgt[i] = vt[(size_t)row * TS + gi];
  }
}

// --------------------------------------------------------------- attn -------
// Block = 64 queries of one (b,h); 4 waves x 16 queries. Swapped QK^T
// (s = mfma(K,Q)) puts each query's full score row on 4 lanes {col, col+16,
// col+32, col+48}: softmax = 2 shuffles, P stays IN REGISTERS (no LDS
// roundtrip). PV: 16x16x32 MFMA where abstract k = grp*8+{0..7} covers keys
// {f0*16+grp*4+0..3, f1*16+grp*4+0..3} in BOTH operands -> two 16-key blocks
// per MFMA, B-frag = lane's own packed P, A-frag = 2x ds_read_b64 from V^T.
__global__ __launch_bounds__(256) void attn_kernel(const bf16* __restrict__ qkv,
                                                   const bf16* __restrict__ vt,
                                                   const bf16* __restrict__ vgt,
                                                   const int* __restrict__ gidx,
                                                   bf16* __restrict__ ctx) {
  constexpr int VST = 216;
  constexpr int VGST = 88;
  __shared__ __attribute__((aligned(16))) char smem[35840];
  bf16* sV = (bf16*)smem;             // 13824 B
  bf16* sVg = (bf16*)(smem + 13824);  //  5632 B
  bf16* sK = (bf16*)(smem + 19456);   // 12288 B
  bf16* sKg = (bf16*)(smem + 31744);  //  4096 B

  const int tid = threadIdx.x, wid = tid >> 6, lane = tid & 63;
  const int grp = lane >> 4, col = lane & 15;
  const int bid = (blockIdx.x & 7) * 1024 + (blockIdx.x >> 3);
  const int tile = bid & 127, h = (bid >> 7) & 15, b = bid >> 11;
  const int t0b = tile * 64;
  const int kbb = t0b - 64;
  const int bh = b * NH + h;
  const bf16* base = qkv + (size_t)b * TS * NQKV;
  const bf16* kpl = base + 512 + h * 32;

  // ---- cooperative staging ----
  #pragma unroll
  for (int it = 0; it < 3; ++it) {             // sK: 768 16B chunks, direct-to-LDS
    const int idx = it * 256 + tid;
    const int row = idx >> 2, part = idx & 3;
    const int tok = min(max(kbb + row, 0), TS - 1);
    gl_lds16(kpl + (size_t)tok * NQKV + ((part ^ (row & 3)) << 3), sK + idx * 8);
  }
  {
    const int row = tid >> 2, part = tid & 3;  // sKg: 256 chunks, direct-to-LDS
    const int gi = gidx[row];
    gl_lds16(kpl + (size_t)gi * NQKV + ((part ^ (row & 3)) << 3), sKg + tid * 8);
  }
  {
    const bf16* vr = vt + (size_t)(bh * HD + (tid >> 3)) * TS + kbb;
    #pragma unroll
    for (int i = 0; i < 4; ++i) {              // sV: 32 rows x 27 chunks
      const int c = i * 8 + (tid & 7);
      if (c < 27) *(bf16x8*)(sV + (tid >> 3) * VST + c * 8) = ld8(vr + c * 8);
    }
  }
  {
    const int row = tid >> 3, c = tid & 7;     // sVg: 256 chunks
    *(bf16x8*)(sVg + row * VGST + c * 8) = ld8(vgt + (size_t)(bh * HD + row) * NG + c * 8);
  }
  __syncthreads();

  // ---- per-wave compute ----
  const int qt = t0b + wid * 16;
  const int offw = wid * 16;

  const bf16x8 qf = ld8(base + (size_t)(qt + col) * NQKV + h * 32 + grp * 8);
  const f32x4 z = {0.f, 0.f, 0.f, 0.f};
  f32x4 s[13];
  #pragma unroll
  for (int f = 0; f < 9; ++f) {
    const int row = offw + f * 16 + col;
    bf16x8 kf = ld8(sK + row * 32 + ((grp ^ (row & 3)) << 3));
    s[f] = MFMA16(kf, qf, z);   // swapped: D[key_local][q]
  }
  #pragma unroll
  for (int f = 0; f < 4; ++f) {
    const int row = f * 16 + col;
    bf16x8 kf = ld8(sKg + row * 32 + ((grp ^ (row & 3)) << 3));
    s[9 + f] = MFMA16(kf, qf, z);
  }
  // lane (grp,col): query q=col, local key j = f*16 + grp*4 + r
  const float scale = 0.17677669529663688f;  // 1/sqrt(32)
  float mx = -3e38f;
  const bool interior = (tile >= 1) & (tile <= 126);
  if (interior) {
    #pragma unroll
    for (int f = 0; f < 13; ++f) {
      #pragma unroll
      for (int r = 0; r < 4; ++r) {
        float v = s[f][r] * scale;
        if (f == 0) v = (grp * 4 + r >= col) ? v : -1e30f;
        if (f == 8) v = (grp * 4 + r <= col) ? v : -1e30f;
        s[f][r] = v;
        mx = fmaxf(mx, v);
      }
    }
  } else {
    #pragma unroll
    for (int f = 0; f < 13; ++f) {
      #pragma unroll
      for (int r = 0; r < 4; ++r) {
        float v = s[f][r] * scale;
        if (f < 9) {
          const int j = f * 16 + grp * 4 + r;
          const int pos = qt - 64 + j;
          const bool valid = (j >= col) & (j <= col + 128) & (pos >= 0) & (pos < TS);
          v = valid ? v : -1e30f;
        }
        s[f][r] = v;
        mx = fmaxf(mx, v);
      }
    }
  }
  mx = fmaxf(mx, __shfl_xor(mx, 16));
  mx = fmaxf(mx, __shfl_xor(mx, 32));
  float sum = 0.f;
  bf16x8 pb[7];  // pairs (0,1),(2,3),(4,5),(6,7),(8,zero),(9,10),(11,12)
  #pragma unroll
  for (int f = 0; f < 13; ++f) {
    const int pr = (f < 9) ? (f >> 1) : (5 + ((f - 9) >> 1));
    const int hf = (f < 9) ? (f & 1) : ((f - 9) & 1);
    #pragma unroll
    for (int r = 0; r < 4; ++r) {
      float p = __expf(s[f][r] - mx);
      sum += p;
      pb[pr][hf * 4 + r] = (__bf16)__float2bfloat16(p);
    }
  }
  #pragma unroll
  for (int r = 0; r < 4; ++r) pb[4][4 + r] = (__bf16)__float2bfloat16(0.f);
  sum += __shfl_xor(sum, 16);
  sum += __shfl_xor(sum, 32);
  const float sm = 1.0f / sum;

  f32x4 c0 = z, c1 = z;
  const bf16* sVr0 = sV + col * VST;
  const bf16* sVr1 = sV + (col + 16) * VST;
  #pragma unroll
  for (int i = 0; i < 5; ++i) {     // local key pairs (32 keys per MFMA)
    const int kk = offw + i * 32 + grp * 4;
    bf16x8 a0 = __builtin_shufflevector(ld4(sVr0 + kk), ld4(sVr0 + kk + 16),
                                        0, 1, 2, 3, 4, 5, 6, 7);
    bf16x8 a1 = __builtin_shufflevector(ld4(sVr1 + kk), ld4(sVr1 + kk + 16),
                                        0, 1, 2, 3, 4, 5, 6, 7);
    c0 = MFMA16(a0, pb[i], c0);
    c1 = MFMA16(a1, pb[i], c1);
  }
  const bf16* sVg0 = sVg + col * VGST;
  const bf16* sVg1 = sVg + (col + 16) * VGST;
  #pragma unroll
  for (int i = 0; i < 2; ++i) {     // global key pairs
    const int kk = i * 32 + grp * 4;
    bf16x8 a0 = __builtin_shufflevector(ld4(sVg0 + kk), ld4(sVg0 + kk + 16),
                                        0, 1, 2, 3, 4, 5, 6, 7);
    bf16x8 a1 = __builtin_shufflevector(ld4(sVg1 + kk), ld4(sVg1 + kk + 16),
                                        0, 1, 2, 3, 4, 5, 6, 7);
    c0 = MFMA16(a0, pb[5 + i], c0);
    c1 = MFMA16(a1, pb[5 + i], c1);
  }
  // lane (grp,col) holds ctx^T[dv = grp*4+r (+16)][q = col]
  const int t = qt + col;
  bf16* op = ctx + ((size_t)(b * TS + t)) * DM + h * 32 + grp * 4;
  ushort4 o0, o1;
  o0.x = b16bits(__float2bfloat16(c0[0] * sm));
  o0.y = b16bits(__float2bfloat16(c0[1] * sm));
  o0.z = b16bits(__float2bfloat16(c0[2] * sm));
  o0.w = b16bits(__float2bfloat16(c0[3] * sm));
  o1.x = b16bits(__float2bfloat16(c1[0] * sm));
  o1.y = b16bits(__float2bfloat16(c1[1] * sm));
  o1.z = b16bits(__float2bfloat16(c1[2] * sm));
  o1.w = b16bits(__float2bfloat16(c1[3] * sm));
  *(ushort4*)op = o0;
  *(ushort4*)(op + 16) = o1;
}

// ------------------------------------------------------------- launch -------
extern "C" void kernel_launch(void* const* d_in, const int* in_sizes, int n_in,
                              void* d_out, int out_size, void* d_ws, size_t ws_size,
                              hipStream_t stream) {
  (void)in_sizes; (void)n_in; (void)out_size; (void)ws_size;
  const float* x = (const float*)d_in[0];
  const float* Wq = (const float*)d_in[1];
  const float* bq = (const float*)d_in[2];
  const float* Wk = (const float*)d_in[3];
  const float* bk = (const float*)d_in[4];
  const float* Wv = (const float*)d_in[5];
  const float* bv = (const float*)d_in[6];
  const float* Wo = (const float*)d_in[7];
  const float* bo = (const float*)d_in[8];
  const int* gidx = (const int*)d_in[9];
  float* out = (float*)d_out;

  char* ws = (char*)d_ws;
  size_t off = 0;
  auto alloc = [&](size_t bytes) -> void* {
    void* p = ws + off;
    off += (bytes + 255) & ~(size_t)255;
    return p;
  };
  bf16* xb = (bf16*)alloc((size_t)BB * TS * DM * 2);       // 32 MB (reused as ctx)
  bf16* Wp = (bf16*)alloc((size_t)NQKV * DM * 2);          // 1.5 MB packed
  bf16* Wp2 = (bf16*)alloc((size_t)DM * DM * 2);           // 0.5 MB packed
  float* bqkv = (float*)alloc((size_t)NQKV * 4);           // 6 KB
  bf16* qkv = (bf16*)alloc((size_t)BB * TS * NQKV * 2);    // 96 MB (V third unused)
  bf16* vta = (bf16*)alloc(((size_t)2048 * TS + 512) * 2); // 32 MB + pad
  bf16* vgt = (bf16*)alloc((size_t)2048 * NG * 2);         // 256 KB
  bf16* ctx = xb;                                          // alias: xb dead after GEMM1
  bf16* vt = vta + 64;                                     // front pad of 64 elems

  prep_kernel<<<dim3(2048), dim3(256), 0, stream>>>(x, Wq, bq, Wk, bk, Wv, bv, Wo,
                                                    xb, Wp, Wp2, bqkv);
  gemm_bias<false, true><<<dim3(3072), dim3(256), 0, stream>>>(xb, Wp, bqkv, qkv, vt,
                                                               BB * TS, NQKV, DM, 384);
  vgt_kernel<<<dim3(512), dim3(256), 0, stream>>>(vt, gidx, vt, vgt);
  attn_kernel<<<dim3(8192), dim3(256), 0, stream>>>(qkv, vt, vgt, gidx, ctx);
  gemm_bias<true, false><<<dim3(1024), dim3(256), 0, stream>>>(ctx, Wp2, bo, out, nullptr,
                                                               BB * TS, DM, DM, 128);
}